// Round 5
// baseline (453.570 us; speedup 1.0000x reference)
//
#include <hip/hip_runtime.h>

#define NB    133
#define NBP   136            // gT f-row stride in shorts: 68 words = 4 mod 32 -> 2-way banks (free)
#define BATCH 256
#define HEADS 8
#define CDIM  128
#define DDIM  1024
#define MROWS (BATCH * NB)   // 34048 = 266*128
#define NDIM  (HEADS * CDIM)
#define BH    (BATCH * HEADS)
#define NKT   32             // K tiles of BK=32

typedef __bf16 bf16_t;
typedef bf16_t bf16x8 __attribute__((ext_vector_type(8)));
typedef float  f32x4  __attribute__((ext_vector_type(4)));

__device__ __forceinline__ unsigned short f2bf(float f) {
  unsigned u = __float_as_uint(f);
  u += 0x7fffu + ((u >> 16) & 1u);
  return (unsigned short)(u >> 16);
}
__device__ __forceinline__ void load_lds16(const void* g, void* l) {
  __builtin_amdgcn_global_load_lds(
      (__attribute__((address_space(1))) void*)(g),
      (__attribute__((address_space(3))) void*)(l), 16, 0, 0);
}
__device__ __forceinline__ void bar() {
  asm volatile("" ::: "memory");
  __builtin_amdgcn_s_barrier();
  asm volatile("" ::: "memory");
}
#define VMWAIT(n) asm volatile("s_waitcnt vmcnt(" #n ")" ::: "memory")

// ---------------- fp32 -> bf16 convert, x and W in one launch ----------------
__global__ __launch_bounds__(256) void cvt_kernel(const float* __restrict__ x,
                                                  const float* __restrict__ W,
                                                  unsigned short* __restrict__ xb,
                                                  unsigned short* __restrict__ wb) {
  const int nx = MROWS * DDIM / 8, nw = NDIM * DDIM / 8;
  int i = blockIdx.x * 256 + threadIdx.x;
  const float* src; unsigned short* dst; int k;
  if (i < nx)           { src = x; dst = xb; k = i; }
  else if (i < nx + nw) { src = W; dst = wb; k = i - nx; }
  else return;
  const float4* s4 = (const float4*)src;
  float4 a = s4[(size_t)k * 2];
  float4 b = s4[(size_t)k * 2 + 1];
  union { unsigned short u[8]; uint4 v; } p;
  p.u[0] = f2bf(a.x); p.u[1] = f2bf(a.y); p.u[2] = f2bf(a.z); p.u[3] = f2bf(a.w);
  p.u[4] = f2bf(b.x); p.u[5] = f2bf(b.y); p.u[6] = f2bf(b.z); p.u[7] = f2bf(b.w);
  ((uint4*)dst)[k] = p.v;
}

// ---------------- adjacency bitmasks, one block per row/col ----------------
__global__ __launch_bounds__(192) void mask_kernel(const float* __restrict__ adj,
                                                   unsigned* __restrict__ rm,
                                                   unsigned* __restrict__ cm) {
  const int tid = threadIdx.x, lane = tid & 63, wv = tid >> 6, blk = blockIdx.x;
  if (blk < 144) {
    const int i = blk;
    bool on = (i < NB) && (tid < NB) && (adj[i * NB + tid] != 0.f);
    unsigned long long bb = __ballot(on);
    if (lane == 0)  rm[i * 6 + wv * 2]     = (unsigned)bb;
    if (lane == 32) rm[i * 6 + wv * 2 + 1] = (unsigned)(bb >> 32);
  } else {
    const int j = blk - 144;
    bool on = (tid < NB) && (adj[tid * NB + j] != 0.f);
    unsigned long long bb = __ballot(on);
    if (lane == 0)  cm[j * 6 + wv * 2]     = (unsigned)bb;
    if (lane == 32) cm[j * 6 + wv * 2 + 1] = (unsigned)(bb >> 32);
  }
}

// ---------------- GEMM: g = x @ W^T, fused si/sj ----------------
// M128 x N256 tile, 256 threads (4 waves, 1M x 4N), wave tile 128x64, BK=32.
// B (W, 2 MB, L2-resident in every XCD) is loaded global->register, double-
// buffered one K-tile ahead -- NO B LDS at all. LDS holds only A: ring of 3
// x 8 KB buffers (28 KB total). ONE barrier per K-tile (only A needs sync).
// Per-CU per K-tile: MFMA ~621 cyc vs LDS ~320 cyc -> MFMA-majority.
// vmcnt ledger (per wave/iter): issue STGA(t+2)[2] + Bload(t+1)[4];
// VMWAIT(6) drains STGA(t+1)+Bload(t) -> A(t+1) complete before the barrier,
// B(t) complete before its MFMAs. Never drains to 0 in the main loop.
// Ring-3 WAR: stage targets the buffer read one barrier ago (R4 discipline).
// A swizzle (64-B rows): LDS slot s of row r holds chunk s ^ ((r>>2)&3);
// read slot = q ^ (li>>2) -> each 16-lane quarter-wave spreads 2 lanes per
// 4-bank group = conflict-free b128 (fixes R4's 6.5M quarter-wave conflicts,
// which used li&3: only {0,2} for even lanes -> 2x bank pile-up).
__global__ __launch_bounds__(256, 2) void gemm_kernel(const unsigned short* __restrict__ xb,
                                                      const unsigned short* __restrict__ wb,
                                                      const float* __restrict__ attn_w,
                                                      unsigned short* __restrict__ gb,
                                                      float* __restrict__ si_ws,
                                                      float* __restrict__ sj_ws) {
  __shared__ __attribute__((aligned(16))) unsigned short Abuf[3][128 * 32];
  __shared__ float sred[2][4][128];

  const int tid = threadIdx.x;
  // bijective XCD swizzle: nwg = 1064 = 8*133 exactly.
  const int orig = blockIdx.x;
  const int wg = (orig & 7) * 133 + (orig >> 3);
  const int bn = wg & 3, bm = wg >> 2;            // 266 m-tiles x 4 n-tiles

  const int lane = tid & 63, w = tid >> 6;        // wave w: cols w*64, rows 0..127
  const int q = lane >> 4, li = lane & 15;

  const unsigned short* Ab = xb + (size_t)bm * 128 * DDIM;

  // A staging: flat chunk f = tid + i*256; row = f>>2, lds slot = f&3,
  // source chunk = slot ^ ((row>>2)&3) = (f&3) ^ ((f>>4)&3).
  int sA0, sA1;
  { int f = tid;       sA0 = (f >> 2) * DDIM + ((((f & 3) ^ ((f >> 4) & 3))) << 3); }
  { int f = tid + 256; sA1 = (f >> 2) * DDIM + ((((f & 3) ^ ((f >> 4) & 3))) << 3); }
#define STGA(dst_, kt_) do { \
    load_lds16(Ab + sA0 + (kt_) * 32, (dst_) + tid * 8); \
    load_lds16(Ab + sA1 + (kt_) * 32, (dst_) + (tid + 256) * 8); \
  } while (0)

  // B direct from global: lane (q,li) of wave w reads W row bn*256+w*64+ni*16+li,
  // k-chunk q. 16 rows x 64 contiguous B per instr; W is L2-hot everywhere.
  const unsigned short* Bp = wb + (size_t)(bn * 256 + w * 64 + li) * DDIM + q * 8;

  // A frag read slot (quarter-wave conflict-free)
  const int asl = (q ^ (li >> 2)) << 3;

  f32x4 acc[8][4] = {};
  bf16x8 a[8], bE[4], bO[4];

  unsigned short* p0 = &Abuf[0][0];
  unsigned short* p1 = &Abuf[1][0];
  unsigned short* p2 = &Abuf[2][0];

#define LDA_(src_) { _Pragma("unroll") for (int mi = 0; mi < 8; ++mi) \
      a[mi] = *(const bf16x8*)&(src_)[(mi * 16 + li) * 32 + asl]; }
#define LDB(dst_, kt_) { _Pragma("unroll") for (int ni = 0; ni < 4; ++ni) \
      dst_[ni] = *(const bf16x8*)(Bp + ni * 16 * DDIM + (kt_) * 32); }
#define MM(bv_) { __builtin_amdgcn_s_setprio(1); \
      _Pragma("unroll") for (int ni = 0; ni < 4; ++ni) \
      _Pragma("unroll") for (int mi = 0; mi < 8; ++mi) \
        acc[mi][ni] = __builtin_amdgcn_mfma_f32_16x16x32_bf16(a[mi], bv_[ni], acc[mi][ni], 0, 0, 0); \
      __builtin_amdgcn_s_setprio(0); }

  // prologue: A tiles 0,1 staged; B(0) -> bE; drain STGA(0) only (vmcnt 8->6)
  STGA(p0, 0); STGA(p1, 1);
  LDB(bE, 0);
  VMWAIT(6);
  bar();

  for (int t = 0; t < 28; t += 2) {
    // even tile t: compute p0, stage A(t+2)->p2, load B(t+1)->bO
    LDA_(p0);
    STGA(p2, t + 2);
    LDB(bO, t + 1);
    VMWAIT(6);            // drains STGA(t+1) + Bload(t)
    bar();
    MM(bE);
    // odd tile t+1: compute p1, stage A(t+3)->p0, load B(t+2)->bE
    LDA_(p1);
    STGA(p0, t + 3);
    LDB(bE, t + 2);
    VMWAIT(6);            // drains STGA(t+2) + Bload(t+1)
    bar();
    MM(bO);
    // rotate ring: next pair's cur tile (t+2) lives in p2
    unsigned short* tmp = p0; p0 = p2; p2 = p1; p1 = tmp;
  }
  // t = 28
  LDA_(p0); STGA(p2, 30); LDB(bO, 29); VMWAIT(6); bar(); MM(bE);
  // t = 29 (last stage: tile 31)
  LDA_(p1); STGA(p0, 31); LDB(bE, 30); VMWAIT(6); bar(); MM(bO);
  { unsigned short* tmp = p0; p0 = p2; p2 = p1; p1 = tmp; }
  // t = 30 (drains STGA(31); compiler waits the bE/bO register deps)
  LDA_(p0); LDB(bO, 31); VMWAIT(6); bar(); MM(bE);
  // t = 31
  LDA_(p1); MM(bO);
#undef STGA
#undef LDA_
#undef LDB
#undef MM

  // ---- fused si/sj: per-head dot with wl/wr; head = bn*2 + (w>>1) ----
  float wlv[4], wrv[4];
#pragma unroll
  for (int ni = 0; ni < 4; ++ni) {
    const int cc = (w & 1) * 64 + ni * 16 + li;   // head-local column
    wlv[ni] = attn_w[cc];
    wrv[ni] = attn_w[CDIM + cc];
  }
#pragma unroll
  for (int mi = 0; mi < 8; ++mi)
#pragma unroll
    for (int rr = 0; rr < 4; ++rr) {
      float pj = 0.f, pi = 0.f;
#pragma unroll
      for (int ni = 0; ni < 4; ++ni) {
        pj += acc[mi][ni][rr] * wlv[ni];
        pi += acc[mi][ni][rr] * wrv[ni];
      }
#pragma unroll
      for (int d = 1; d < 16; d <<= 1) {
        pj += __shfl_xor(pj, d);
        pi += __shfl_xor(pi, d);
      }
      if (li == 0) {
        sred[0][w][mi * 16 + q * 4 + rr] = pj;
        sred[1][w][mi * 16 + q * 4 + rr] = pi;
      }
    }
  __syncthreads();
#pragma unroll
  for (int idx0 = 0; idx0 < 2; ++idx0) {
    const int idx = idx0 * 256 + tid;     // 512 items: 2(which) x 2(hw) x 128(rows)
    const int row = idx & 127;
    const int hw = (idx >> 7) & 1;
    const int which = idx >> 8;
    const float v = sred[which][hw * 2][row] + sred[which][hw * 2 + 1][row];
    const int rg = bm * 128 + row;
    const int b = rg / NB, n = rg - b * NB;
    const int h = bn * 2 + hw;
    float* dst = which ? si_ws : sj_ws;
    dst[(b * HEADS + h) * NB + n] = v;
  }

  // ---- store g bf16, normal [row][col] layout ----
#pragma unroll
  for (int mi = 0; mi < 8; ++mi)
#pragma unroll
    for (int ni = 0; ni < 4; ++ni) {
      const int col = bn * 256 + w * 64 + ni * 16 + li;
      const size_t row0 = (size_t)(bm * 128 + mi * 16 + q * 4);
#pragma unroll
      for (int rr = 0; rr < 4; ++rr)
        gb[(row0 + rr) * NDIM + col] = f2bf(acc[mi][ni][rr]);
    }
}

// ---------------- column softmax stats: smrg[bh][j] = (sj_j, m_j + ln(denom_j)) ----------------
__global__ __launch_bounds__(192) void stats_kernel(const float* __restrict__ si_ws,
                                                    const float* __restrict__ sj_ws,
                                                    const unsigned* __restrict__ cm,
                                                    float2* __restrict__ smrg) {
  __shared__ float siL[NB];
  const int tid = threadIdx.x;
  const int base = blockIdx.x * NB;
  if (tid < NB) siL[tid] = si_ws[base + tid];
  __syncthreads();
  if (tid >= 160) return;
  float2 o = {0.f, 0.f};
  if (tid < NB) {
    const int j = tid;
    const float sjv = sj_ws[base + j];
    float m = -3.0e38f;
#pragma unroll
    for (int wd = 0; wd < 5; ++wd) {
      unsigned bits = cm[j * 6 + wd];
      while (bits) {
        const int i = __ffs(bits) - 1; bits &= bits - 1;
        float e = siL[wd * 32 + i] + sjv;
        e = e > 0.f ? e : 0.2f * e;
        m = fmaxf(m, e);
      }
    }
    float s = 0.f;
#pragma unroll
    for (int wd = 0; wd < 5; ++wd) {
      unsigned bits = cm[j * 6 + wd];
      while (bits) {
        const int i = __ffs(bits) - 1; bits &= bits - 1;
        float e = siL[wd * 32 + i] + sjv;
        e = e > 0.f ? e : 0.2f * e;
        s += __expf(e - m);
      }
    }
    o.x = sjv;
    o.y = m + __logf(s);   // weight = exp(e - o.y): rd folded into the exponent
  }
  smrg[(size_t)blockIdx.x * 160 + tid] = o;
}

// ---------------- aggregation: block = (b, h, f-half); LDS transpose of g ----------------
__global__ __launch_bounds__(256) void agg_kernel(const unsigned short* __restrict__ gb,
                                                  const float* __restrict__ si_ws,
                                                  const float2* __restrict__ smrg,
                                                  const unsigned* __restrict__ rm,
                                                  float* __restrict__ out) {
  __shared__ __attribute__((aligned(16))) unsigned short gTl[64 * NBP + 32]; // [f][j]
  __shared__ __attribute__((aligned(8))) float2 smrL[160];
  const int tid = threadIdx.x;
  const int bh = blockIdx.x >> 1, fh = blockIdx.x & 1;
  const int b = bh >> 3, h = bh & 7;
  const int base = bh * NB;

  // zero pad: cols 133..135 of every f-row + 32-short tail (MFMA K-overreads hit these)
  if (tid < 64) {
    gTl[tid * NBP + 133] = 0;
    *(unsigned*)&gTl[tid * NBP + 134] = 0;
  }
  if (tid >= 64 && tid < 80) *(unsigned*)&gTl[64 * NBP + 2 * (tid - 64)] = 0;
  if (tid < 160) smrL[tid] = smrg[(size_t)bh * 160 + tid];

  // coalesced read (16 lanes x 8B per j-row) + transpose via b16 LDS writes
  const unsigned short* gsrc = gb + (size_t)(b * NB) * NDIM + h * CDIM + fh * 64;
  for (int u = tid; u < NB * 16; u += 256) {
    const int j = u >> 4, fg = u & 15;
    const uint2 d = *(const uint2*)(gsrc + (size_t)j * NDIM + fg * 4);
    const int f0 = fg * 4;
    gTl[(f0 + 0) * NBP + j] = (unsigned short)(d.x);
    gTl[(f0 + 1) * NBP + j] = (unsigned short)(d.x >> 16);
    gTl[(f0 + 2) * NBP + j] = (unsigned short)(d.y);
    gTl[(f0 + 3) * NBP + j] = (unsigned short)(d.y >> 16);
  }
  __syncthreads();

  const int lane = tid & 63, wv = tid >> 6, q = lane >> 4, li = lane & 15;
  for (int mt = wv; mt < 9; mt += 4) {
    const int il = mt * 16 + li;
    const float si_r = si_ws[base + (il < NB ? il : NB - 1)];
    const unsigned* rmr = rm + il * 6;
    f32x4 acc[4] = {};
#pragma unroll
    for (int ks = 0; ks < 5; ++ks) {
      const int j0 = ks * 32 + q * 8;
      const unsigned bits = rmr[ks] >> (q * 8);
      bf16x8 afv;
#pragma unroll
      for (int jj = 0; jj < 8; ++jj) {
        const float2 sv = smrL[j0 + jj];
        float e = si_r + sv.x;
        e = e > 0.f ? e : 0.2f * e;
        const float wgt = ((bits >> jj) & 1u) ? __expf(e - sv.y) : 0.f;
        afv[jj] = (bf16_t)wgt;
      }
#pragma unroll
      for (int n = 0; n < 4; ++n) {
        const bf16x8 bv = *(const bf16x8*)&gTl[(n * 16 + li) * NBP + j0];
        acc[n] = __builtin_amdgcn_mfma_f32_16x16x32_bf16(afv, bv, acc[n], 0, 0, 0);
      }
    }
    float* obase = out + (size_t)(b * NB) * NDIM + h * CDIM + fh * 64;
#pragma unroll
    for (int n = 0; n < 4; ++n)
#pragma unroll
      for (int rr = 0; rr < 4; ++rr) {
        const int i = mt * 16 + q * 4 + rr;
        if (i < NB) obase[(size_t)i * NDIM + n * 16 + li] = acc[n][rr];
      }
  }
}

extern "C" void kernel_launch(void* const* d_in, const int* in_sizes, int n_in,
                              void* d_out, int out_size, void* d_ws, size_t ws_size,
                              hipStream_t stream) {
  const float* x      = (const float*)d_in[0];
  const float* W      = (const float*)d_in[1];
  const float* attn_w = (const float*)d_in[2];
  const float* adj    = (const float*)d_in[3];
  float* out = (float*)d_out;
  char* ws = (char*)d_ws;

  // workspace layout (bytes), ~143.7 MB; smrg overlays xb (xb dead after gemm)
  unsigned short* xb = (unsigned short*)(ws + 0);            // 69,730,304
  unsigned short* wb = (unsigned short*)(ws + 69730304);     //  2,097,152
  unsigned short* gb = (unsigned short*)(ws + 71827456);     // 69,730,304
  float* si = (float*)(ws + 141557760);                      //  1,089,536
  float* sj = (float*)(ws + 142647296);                      //  1,089,536
  unsigned* rm = (unsigned*)(ws + 143736832);                //      3,456
  unsigned* cm = (unsigned*)(ws + 143740288);                //      3,192
  float2* smrg = (float2*)(ws + 0);                          //  2,621,440 (overlay)

  const int ncvt = (MROWS * DDIM + NDIM * DDIM) / 8;
  cvt_kernel<<<(ncvt + 255) / 256, 256, 0, stream>>>(x, W, xb, wb);
  mask_kernel<<<277, 192, 0, stream>>>(adj, rm, cm);
  gemm_kernel<<<266 * 4, 256, 0, stream>>>(xb, wb, attn_w, gb, si, sj);
  stats_kernel<<<BH, 192, 0, stream>>>(si, sj, cm, smrg);
  agg_kernel<<<BH * 2, 256, 0, stream>>>(gb, si, smrg, rm, out);
}